// Round 1
// baseline (514.821 us; speedup 1.0000x reference)
//
#include <hip/hip_runtime.h>

#define PI_F 3.14159265358979323846f

// out[b][p] = cos( (sum of 48 floats) * pi/(48*255) - pi/2 ), where the 48
// floats are the 16-float contiguous chunk at (c*64+p)*16 for c=0,1,2.
//
// Wave-per-batch scheme (no LDS, no barriers):
//   lane loads float4 #(lane + 64k), k=0..11  -> 12 contiguous 1KB wave-loads,
//   12 KB in flight per wave (deep MLP).
//   float4 f belongs to chunk f>>2; lanes 4j..4j+3 at step k all hold pieces of
//   chunk (j + 16k). Quad butterfly (xor1, xor2 -> DPP, near-free) gives the
//   chunk sum s[k] replicated in the 4 lanes.
//   chunk = c*64 + p with p = j + 16*(k&3), c = k>>2: the three channels of
//   patch p live in the SAME lane group j = p&15 at k = t, t+4, t+8 (t=p>>4).
//   So out[p] = s[t] + s[t+4] + s[t+8] -- two register adds, lane r of the
//   group takes t = r. Every lane writes exactly one output (permuted within a
//   contiguous 256B segment -> still full-line coalesced).
__global__ __launch_bounds__(256) void qa_pool_cos_kernel(
    const float4* __restrict__ in4, float* __restrict__ out, int B)
{
    const int waves_per_block = 256 / 64;
    int lane   = threadIdx.x & 63;
    int wave0  = blockIdx.x * waves_per_block + (threadIdx.x >> 6);
    int nwaves = gridDim.x * waves_per_block;

    int j = lane >> 2;       // lane group 0..15
    int t = lane & 3;        // which of the 4 outputs this lane finalizes
    int q = j + (t << 4);    // output index 0..63 (bijective over lanes)

    for (int b = wave0; b < B; b += nwaves) {
        const float4* src = in4 + (size_t)b * 768;

        float s[12];
        #pragma unroll
        for (int k = 0; k < 12; ++k) {
            float4 v = src[lane + 64 * k];
            s[k] = (v.x + v.y) + (v.z + v.w);
        }

        // quad butterfly: chunk sum replicated across each aligned 4-lane group
        #pragma unroll
        for (int k = 0; k < 12; ++k) {
            s[k] += __shfl_xor(s[k], 1, 64);
            s[k] += __shfl_xor(s[k], 2, 64);
        }

        // channel combine in registers (chunks p, p+64, p+128 -> k = t, t+4, t+8)
        float a0 = s[0] + s[4] + s[8];
        float a1 = s[1] + s[5] + s[9];
        float a2 = s[2] + s[6] + s[10];
        float a3 = s[3] + s[7] + s[11];

        // static select of a[t] (predicated, no runtime array indexing)
        float lo  = (t & 1) ? a1 : a0;
        float hi  = (t & 1) ? a3 : a2;
        float tot = (t & 2) ? hi : lo;

        float ang = tot * (PI_F / (48.0f * 255.0f)) - (PI_F * 0.5f);
        out[(size_t)b * 64 + q] = __cosf(ang);
    }
}

extern "C" void kernel_launch(void* const* d_in, const int* in_sizes, int n_in,
                              void* d_out, int out_size, void* d_ws, size_t ws_size,
                              hipStream_t stream) {
    const float4* in4 = (const float4*)d_in[0];
    float*        out = (float*)d_out;

    int B = out_size / 64;                 // 32768 batch elements
    int blocks = 2048;                     // grid-stride: 8192 waves, 4 batches/wave
    qa_pool_cos_kernel<<<blocks, 256, 0, stream>>>(in4, out, B);
}

// Round 3
// 488.276 us; speedup vs baseline: 1.0544x; 1.0544x over previous
//
#include <hip/hip_runtime.h>

#define PI_F 3.14159265358979323846f

// out[b][p] = cos( (sum of 48 floats) * pi/(48*255) - pi/2 ), where the 48
// floats are the 16-float contiguous chunks at (c*64+p)*16 for c=0,1,2.
//
// Wave-per-batch scheme (no LDS, no barriers):
//   lane loads float4 #(lane + 64k), k=0..11  -> 12 contiguous 1KB wave-loads,
//   12 KB in flight per wave (deep MLP). 2048 blocks x 256 thr = 32 waves/CU
//   (max occupancy); per-CU bytes in flight ~384 KB >> ~9 KB needed to cover
//   ~900cy HBM latency at 10 B/cy/CU -> HBM-roofline structure (403 MB -> ~64us).
//
//   float4 f belongs to 16-float chunk f>>2; lanes 4j..4j+3 at step k hold the
//   4 pieces of chunk (j + 16k). Quad butterfly (xor1, xor2 -> DPP, near-free)
//   replicates the chunk sum across the 4 lanes.
//   chunk = c*64 + p with p = j + 16*(k&3), c = k>>2: the three channels of
//   patch p live in the SAME 4-lane group j = p&15 at k = t, t+4, t+8 (t=p>>4).
//   So out[p] = s[t]+s[t+4]+s[t+8] -- two register adds; lane r of the group
//   takes t = r. Every lane writes exactly one output (permutation within a
//   contiguous 256B segment -> full-line coalesced store).
//
// Input is streamed exactly once -> nontemporal loads (skip L2/L3 pollution).
// NOTE: __builtin_nontemporal_load requires a NATIVE clang vector type, not
// HIP_vector_type<float,4> -> cast to ext_vector_type(4) float.
typedef float fvec4 __attribute__((ext_vector_type(4)));

__global__ __launch_bounds__(256) void qa_pool_cos_kernel(
    const fvec4* __restrict__ in4, float* __restrict__ out, int B)
{
    const int waves_per_block = 256 / 64;
    int lane   = threadIdx.x & 63;
    int wave0  = blockIdx.x * waves_per_block + (threadIdx.x >> 6);
    int nwaves = gridDim.x * waves_per_block;

    int j = lane >> 2;       // lane group 0..15
    int t = lane & 3;        // which of the 4 patch-outputs this lane finalizes
    int q = j + (t << 4);    // output index 0..63 (bijective over lanes)

    for (int b = wave0; b < B; b += nwaves) {
        const fvec4* src = in4 + (size_t)b * 768;

        float s[12];
        #pragma unroll
        for (int k = 0; k < 12; ++k) {
            fvec4 v = __builtin_nontemporal_load(&src[lane + 64 * k]);
            s[k] = (v.x + v.y) + (v.z + v.w);
        }

        // quad butterfly: chunk sum replicated across each aligned 4-lane group
        #pragma unroll
        for (int k = 0; k < 12; ++k) {
            s[k] += __shfl_xor(s[k], 1, 64);
            s[k] += __shfl_xor(s[k], 2, 64);
        }

        // channel combine in registers (chunks p, p+64, p+128 -> k = t, t+4, t+8)
        float a0 = s[0] + s[4] + s[8];
        float a1 = s[1] + s[5] + s[9];
        float a2 = s[2] + s[6] + s[10];
        float a3 = s[3] + s[7] + s[11];

        // static select of a[t] (predicated, no runtime array indexing)
        float lo  = (t & 1) ? a1 : a0;
        float hi  = (t & 1) ? a3 : a2;
        float tot = (t & 2) ? hi : lo;

        float ang = tot * (PI_F / (48.0f * 255.0f)) - (PI_F * 0.5f);
        __builtin_nontemporal_store(__cosf(ang), &out[(size_t)b * 64 + q]);
    }
}

extern "C" void kernel_launch(void* const* d_in, const int* in_sizes, int n_in,
                              void* d_out, int out_size, void* d_ws, size_t ws_size,
                              hipStream_t stream) {
    const fvec4* in4 = (const fvec4*)d_in[0];
    float*       out = (float*)d_out;

    int B = out_size / 64;                 // 32768 batch elements
    int blocks = 2048;                     // 8192 waves = 32 waves/CU, 4 batches/wave
    qa_pool_cos_kernel<<<blocks, 256, 0, stream>>>(in4, out, B);
}